// Round 6
// baseline (1931.031 us; speedup 1.0000x reference)
//
#include <hip/hip_runtime.h>
#include <hip/hip_fp16.h>

#define H 1024
#define NLEV 17
#define OD 5
#define TOTD 85
#define NB 4096

typedef _Float16 half8 __attribute__((ext_vector_type(8)));
typedef float f32x4 __attribute__((ext_vector_type(4)));

__device__ __forceinline__ void g2l16(const void* g, void* l) {
  __builtin_amdgcn_global_load_lds((const __attribute__((address_space(1))) unsigned*)g,
                                   (__attribute__((address_space(3))) unsigned*)l, 16, 0, 0);
}

// Block GEMM: C(8192x1024) = act(A @ W + bias), W as W^T [n][k] f16.
// R1-proven structure: 128x128 tile, 4 waves 2Mx2N, single-buffered LDS,
// global_load_lds w=16, XOR swizzle both sides, 2 blocks/CU.
// FUSE: instead of writing C, dot the relu'd row-slice with Wout and
// atomicAdd partials into tot (the output projection, fused).
template<int NT, bool RELU, bool FUSE>
__global__ __launch_bounds__(256, 2)
void gemm_k(const _Float16* __restrict__ A, int ldaB,
            const _Float16* __restrict__ B0, const _Float16* __restrict__ B1, int ldbB,
            const float* __restrict__ bias0, const float* __restrict__ bias1,
            _Float16* __restrict__ C,
            const float* __restrict__ Wout_f, const float* __restrict__ Wout_b,
            const float* __restrict__ bout_f, const float* __restrict__ bout_b,
            int lev, float* __restrict__ tot) {
  __shared__ _Float16 sA[128 * 64];
  __shared__ _Float16 sB[128 * 64];
  const int tid = threadIdx.x;
  const int lane = tid & 63;
  const int wave = tid >> 6;
  const int wm = wave >> 1, wn = wave & 1;
  const int mt = blockIdx.x, nt = blockIdx.y;
  const _Float16* Bp = (mt < 32) ? B0 : B1;
  const float* bias = (mt < 32) ? bias0 : bias1;

  char* sAc = (char*)sA;
  char* sBc = (char*)sB;

  const int srow = (lane >> 3);
  const int scb = (lane & 7) << 4;

  f32x4 acc[4][4];
#pragma unroll
  for (int m = 0; m < 4; ++m)
#pragma unroll
    for (int n = 0; n < 4; ++n) acc[m][n] = 0.f;

  const char* Ab = (const char*)A + (size_t)(mt * 128) * ldaB;
  const char* Bb = (const char*)Bp + (size_t)(nt * 128) * ldbB;

  for (int ks = 0; ks < NT; ++ks) {
    const int kB = ks << 7;
#pragma unroll
    for (int t = 0; t < 4; ++t) {
      int chunk = wave * 4 + t;
      int row = chunk * 8 + srow;
      int off = kB + (scb ^ ((row & 7) << 4));
      g2l16(Ab + (size_t)row * ldaB + off, sAc + chunk * 1024);
      g2l16(Bb + (size_t)row * ldbB + off, sBc + chunk * 1024);
    }
    __syncthreads();
#pragma unroll
    for (int h = 0; h < 2; ++h) {
      half8 af[4], bf[4];
      int kb = h * 64 + ((lane >> 4) << 4);
#pragma unroll
      for (int m = 0; m < 4; ++m) {
        int row = wm * 64 + m * 16 + (lane & 15);
        af[m] = *(const half8*)(sAc + row * 128 + (kb ^ ((row & 7) << 4)));
      }
#pragma unroll
      for (int n = 0; n < 4; ++n) {
        int row = wn * 64 + n * 16 + (lane & 15);
        bf[n] = *(const half8*)(sBc + row * 128 + (kb ^ ((row & 7) << 4)));
      }
#pragma unroll
      for (int m = 0; m < 4; ++m)
#pragma unroll
        for (int n = 0; n < 4; ++n)
          acc[m][n] = __builtin_amdgcn_mfma_f32_16x16x32_f16(af[m], bf[n], acc[m][n], 0, 0, 0);
    }
    __syncthreads();
  }

  // epilogue: C/D layout col=lane&15, row=(lane>>4)*4+reg
  const int r0 = mt * 128 + wm * 64 + ((lane >> 4) << 2);
  int cols[4];
  float bv[4];
#pragma unroll
  for (int n = 0; n < 4; ++n) {
    cols[n] = nt * 128 + wn * 64 + n * 16 + (lane & 15);
    bv[n] = bias[cols[n]];
  }
  float wo[4][OD];
  const float* boB = nullptr;
  if constexpr (FUSE) {
    const float* WoB = ((mt >= 32) ? Wout_b : Wout_f) + (size_t)lev * H * OD;
#pragma unroll
    for (int n = 0; n < 4; ++n)
#pragma unroll
      for (int d = 0; d < OD; ++d) wo[n][d] = WoB[cols[n] * OD + d];
    boB = ((mt >= 32) ? bout_b : bout_f) + lev * OD;
  }
#pragma unroll
  for (int m = 0; m < 4; ++m) {
#pragma unroll
    for (int r = 0; r < 4; ++r) {
      float p[OD] = {0.f, 0.f, 0.f, 0.f, 0.f};
#pragma unroll
      for (int n = 0; n < 4; ++n) {
        float v = acc[m][n][r] + bv[n];
        if (RELU) v = fmaxf(v, 0.f);
        if constexpr (!FUSE) {
          C[(size_t)(r0 + m * 16 + r) * H + cols[n]] = (_Float16)v;
        } else {
#pragma unroll
          for (int d = 0; d < OD; ++d) p[d] += v * wo[n][d];
        }
      }
      if constexpr (FUSE) {
#pragma unroll
        for (int d = 0; d < OD; ++d) {
          p[d] += __shfl_xor(p[d], 1);
          p[d] += __shfl_xor(p[d], 2);
          p[d] += __shfl_xor(p[d], 4);
          p[d] += __shfl_xor(p[d], 8);
        }
        if ((lane & 15) == 0) {
          int row = r0 + m * 16 + r;
          int bb = row & 4095;
          int dir = row >> 12;
          float* tp = tot + (size_t)dir * NB * TOTD + (size_t)bb * TOTD + lev * OD;
#pragma unroll
          for (int d = 0; d < OD; ++d) {
            float add = p[d];
            if (nt == 0 && wn == 0) add += boB[d];
            atomicAdd(tp + d, add);
          }
        }
      }
    }
  }
}

// Input GEMM for level lev: A rows are [x16 | tot-cols | zeros] built directly
// in registers (no LDS, no barriers). B = WinT [2*17][1024][128] f16.
__global__ __launch_bounds__(256)
void gemmin_k(const _Float16* __restrict__ x16, const float* __restrict__ tot,
              const _Float16* __restrict__ WinT,
              const float* __restrict__ bin_f, const float* __restrict__ bin_b,
              int lev, int nsteps, _Float16* __restrict__ Cout) {
  const int tid = threadIdx.x;
  const int lane = tid & 63;
  const int wave = tid >> 6;
  const int wm = wave >> 1, wn = wave & 1;
  const int mt = blockIdx.x;  // 0..63
  const int nt = blockIdx.y;  // 0..7
  const int dir = mt >> 5;
  const float* bias = dir ? bin_b : bin_f;
  const _Float16* Wl = WinT + ((size_t)(dir * NLEV + lev) << 17);
  const int cl = lane & 15;
  const int kg = lane >> 4;
  const int rbase = mt * 128 + wm * 64;

  f32x4 acc[4][4];
#pragma unroll
  for (int m = 0; m < 4; ++m)
#pragma unroll
    for (int n = 0; n < 4; ++n) acc[m][n] = 0.f;

#pragma unroll 1
  for (int s = 0; s < nsteps; ++s) {
    const int kc = s * 32 + kg * 8;
    half8 aF[4], bF[4];
#pragma unroll
    for (int m = 0; m < 4; ++m) {
      int b = (rbase + m * 16 + cl) & 4095;
      if (kc < 16) {
        aF[m] = *(const half8*)(x16 + b * 16 + kc);
      } else {
        const float* tp = tot + (size_t)dir * NB * TOTD + (size_t)b * TOTD + (kc - 16);
        half8 h;
#pragma unroll
        for (int e = 0; e < 8; ++e) h[e] = (_Float16)tp[e];
        aF[m] = h;
      }
    }
#pragma unroll
    for (int n = 0; n < 4; ++n) {
      int col = nt * 128 + wn * 64 + n * 16 + cl;
      bF[n] = *(const half8*)(Wl + (size_t)col * 128 + kc);
    }
#pragma unroll
    for (int m = 0; m < 4; ++m)
#pragma unroll
      for (int n = 0; n < 4; ++n)
        acc[m][n] = __builtin_amdgcn_mfma_f32_16x16x32_f16(aF[m], bF[n], acc[m][n], 0, 0, 0);
  }

  const int r0 = mt * 128 + wm * 64 + (kg << 2);
#pragma unroll
  for (int n = 0; n < 4; ++n) {
    int col = nt * 128 + wn * 64 + n * 16 + cl;
    float bvn = bias[col];
#pragma unroll
    for (int m = 0; m < 4; ++m)
#pragma unroll
      for (int r = 0; r < 4; ++r)
        Cout[(size_t)(r0 + m * 16 + r) * H + col] = (_Float16)(acc[m][n][r] + bvn);
  }
}

__global__ __launch_bounds__(128)
void attn_k(const float* __restrict__ tot, const float* __restrict__ W1,
            const float* __restrict__ W2, const float* __restrict__ W3,
            const float* __restrict__ W4, const float* __restrict__ b4,
            float* __restrict__ out) {
  __shared__ float tf[5][17], tbr[5][17];
  __shared__ float q[17][5], k2[5][17], vv[17][5];
  __shared__ float sc[17][17];
  __shared__ float res[85];
  int b = blockIdx.x, tid = threadIdx.x;
  const float* tfp = tot + (size_t)b * TOTD;
  const float* tbp = tot + (size_t)NB * TOTD + (size_t)b * TOTD;
  if (tid < 85) {
    int c = tid / 17, t = tid % 17;
    tf[c][t] = tfp[tid];
    tbr[c][t] = tbp[c * 17 + (16 - t)];
  }
  __syncthreads();
  if (tid < 85) {
    int t = tid / 5, e = tid % 5;
    float qa = 0, ka = 0, va = 0;
#pragma unroll
    for (int c = 0; c < 5; ++c) {
      qa += tf[c][t] * W1[c * 5 + e];
      ka += tbr[c][t] * W2[c * 5 + e];
      va += tbr[c][t] * W3[c * 5 + e];
    }
    q[t][e] = qa; k2[e][t] = ka; vv[t][e] = va;
  }
  __syncthreads();
  for (int idx = tid; idx < 289; idx += 128) {
    int t = idx / 17, s = idx % 17;
    float a = 0;
#pragma unroll
    for (int e = 0; e < 5; ++e) a += q[t][e] * k2[e][s];
    sc[t][s] = a;
  }
  __syncthreads();
  if (tid < 17) {
    int s = tid;
    float m = -1e30f;
#pragma unroll
    for (int t = 0; t < 17; ++t) m = fmaxf(m, sc[t][s]);
    float ex[17];
    float sum = 0;
#pragma unroll
    for (int t = 0; t < 17; ++t) { ex[t] = expf(sc[t][s] - m); sum += ex[t]; }
    float inv = 1.f / sum;
#pragma unroll
    for (int t = 0; t < 17; ++t) sc[t][s] = ex[t] * inv;
  }
  __syncthreads();
  if (tid < 85) {
    int t = tid / 5, e = tid % 5;
    float a = 0;
#pragma unroll
    for (int s = 0; s < 17; ++s) a += sc[t][s] * vv[s][e];
    res[tid] = a;
  }
  __syncthreads();
  if (tid < 85) {
    float a = b4[tid];
    for (int s = 0; s < 85; ++s) a += res[s] * W4[s * 85 + tid];
    out[(size_t)b * TOTD + tid] = a;
  }
}

// Coalesced LDS-tiled transpose: Wblk [3][1024k][1024n] f32 -> WT [3][n][k] f16
__global__ __launch_bounds__(256)
void prep_wblkT(const float* __restrict__ W, _Float16* __restrict__ WT) {
  __shared__ float tile[32][33];
  const int j = blockIdx.z;
  const int n0 = blockIdx.x * 32, k0 = blockIdx.y * 32;
  const int c = threadIdx.x & 31, r8 = threadIdx.x >> 5;
  const float* Wj = W + ((size_t)j << 20);
  _Float16* WTj = WT + ((size_t)j << 20);
#pragma unroll
  for (int i = 0; i < 4; ++i) {
    int r = r8 + i * 8;
    tile[r][c] = Wj[(size_t)(k0 + r) * 1024 + n0 + c];
  }
  __syncthreads();
#pragma unroll
  for (int i = 0; i < 4; ++i) {
    int r = r8 + i * 8;
    WTj[(size_t)(n0 + r) * 1024 + k0 + c] = (_Float16)tile[c][r];
  }
}

// Win_f/Win_b [17][96][1024] f32 -> WinT [2*17][1024][128] f16 (k padded to 128)
__global__ __launch_bounds__(256)
void prep_winT(const float* __restrict__ Wf, const float* __restrict__ Wb,
               _Float16* __restrict__ WT) {
  __shared__ float tile[32][33];
  const int z = blockIdx.z;  // 0..33
  const int d = z / NLEV, lev = z % NLEV;
  const int n0 = blockIdx.x * 32, k0 = blockIdx.y * 32;
  const float* W = (d ? Wb : Wf) + (size_t)lev * 96 * 1024;
  _Float16* WTl = WT + ((size_t)(d * NLEV + lev) << 17);
  const int c = threadIdx.x & 31, r8 = threadIdx.x >> 5;
#pragma unroll
  for (int i = 0; i < 4; ++i) {
    int r = r8 + i * 8;
    int k = k0 + r;
    tile[r][c] = (k < 96) ? W[(size_t)k * 1024 + n0 + c] : 0.f;
  }
  __syncthreads();
#pragma unroll
  for (int i = 0; i < 4; ++i) {
    int r = r8 + i * 8;
    WTl[(size_t)(n0 + r) * 128 + k0 + c] = (_Float16)tile[c][r];
  }
}

__global__ __launch_bounds__(256)
void prep_x16(const float* __restrict__ x, _Float16* __restrict__ x16) {
  int idx = blockIdx.x * 256 + threadIdx.x;  // < 65536
  x16[idx] = (_Float16)x[idx];
}

__global__ __launch_bounds__(256)
void zero_tot(float* __restrict__ tot) {
  int idx = blockIdx.x * 256 + threadIdx.x;  // < 696320
  tot[idx] = 0.f;
}

extern "C" void kernel_launch(void* const* d_in, const int* in_sizes, int n_in,
                              void* d_out, int out_size, void* d_ws, size_t ws_size,
                              hipStream_t stream) {
  const float* x = (const float*)d_in[0];
  const float* bin_f = (const float*)d_in[2];
  const float* bin_b = (const float*)d_in[4];
  const float* Wblk = (const float*)d_in[5];
  const float* bblk = (const float*)d_in[6];
  const float* Wout_f = (const float*)d_in[7];
  const float* bout_f = (const float*)d_in[8];
  const float* Wout_b = (const float*)d_in[9];
  const float* bout_b = (const float*)d_in[10];
  const float* W1 = (const float*)d_in[11];
  const float* W2 = (const float*)d_in[12];
  const float* W3 = (const float*)d_in[13];
  const float* W4 = (const float*)d_in[14];
  const float* b4 = (const float*)d_in[15];
  float* out = (float*)d_out;

  char* ws = (char*)d_ws;
  size_t off = 0;
  auto alloc = [&](size_t bytes) {
    void* p = ws + off;
    off += (bytes + 255) & ~(size_t)255;
    return p;
  };
  _Float16* WblkT = (_Float16*)alloc((size_t)3 * 1024 * 1024 * 2);
  _Float16* WinT = (_Float16*)alloc((size_t)2 * NLEV * 1024 * 128 * 2);
  _Float16* x16 = (_Float16*)alloc((size_t)4096 * 16 * 2);
  _Float16* hA = (_Float16*)alloc((size_t)8192 * 1024 * 2);
  _Float16* hB = (_Float16*)alloc((size_t)8192 * 1024 * 2);
  float* tot = (float*)alloc((size_t)2 * NB * TOTD * 4);

  prep_wblkT<<<dim3(32, 32, 3), dim3(256), 0, stream>>>(Wblk, WblkT);
  prep_winT<<<dim3(32, 4, 2 * NLEV), dim3(256), 0, stream>>>(
      (const float*)d_in[1], (const float*)d_in[3], WinT);
  prep_x16<<<dim3(256), dim3(256), 0, stream>>>(x, x16);
  zero_tot<<<dim3(2720), dim3(256), 0, stream>>>(tot);

  dim3 ggrid(64, 8), gblk(256);
  for (int i = 0; i < NLEV; ++i) {
    int nsteps = (16 + 5 * i + 31) / 32;
    gemmin_k<<<ggrid, gblk, 0, stream>>>(x16, tot, WinT, bin_f, bin_b, i, nsteps, hA);
    gemm_k<16, true, false><<<ggrid, gblk, 0, stream>>>(
        hA, H * 2, WblkT, WblkT, H * 2, bblk, bblk, hB,
        nullptr, nullptr, nullptr, nullptr, 0, nullptr);
    gemm_k<16, true, false><<<ggrid, gblk, 0, stream>>>(
        hB, H * 2, WblkT + (1 << 20), WblkT + (1 << 20), H * 2, bblk + H, bblk + H, hA,
        nullptr, nullptr, nullptr, nullptr, 0, nullptr);
    gemm_k<16, true, true><<<ggrid, gblk, 0, stream>>>(
        hA, H * 2, WblkT + (2 << 20), WblkT + (2 << 20), H * 2, bblk + 2 * H, bblk + 2 * H, hB,
        Wout_f, Wout_b, bout_f, bout_b, i, tot);
  }
  attn_k<<<dim3(NB), dim3(128), 0, stream>>>(tot, W1, W2, W3, W4, b4, out);
}